// Round 1
// baseline (41.863 us; speedup 1.0000x reference)
//
#include <hip/hip_runtime.h>

// sym2 filters, pre-reversed (pytorch_wavelets cross-correlation convention)
__device__ __constant__ float H0R[4] = { 0.48296291314453416f,  0.8365163037378079f,
                                         0.22414386804185735f, -0.12940952255126037f};
__device__ __constant__ float H1R[4] = {-0.12940952255126037f, -0.22414386804185735f,
                                         0.8365163037378079f,  -0.48296291314453416f};

// Level geometry (N=50): 50 -> 26 -> 14 -> 8, pad = 4 (ph=2) at every level, no odd pad.

// Kernel 1: build the folded matrix M[k][c][n] (5 x 3 x 50 = 750 floats) in d_ws.
// A[j][n] = response of leaf j (j = band1*4+band2*2+band3, s in [0,8)) to basis e_n.
__global__ __launch_bounds__(256) void build_M(const float* __restrict__ W,
                                               float* __restrict__ Mout) {
    __shared__ float sL1[2 * 26 * 50];   // [band][m][n]
    __shared__ float sL2[4 * 14 * 50];   // [j2][m][n]
    __shared__ float sA [8 * 8 * 50];    // [(j3*8+s)][n]
    const int tid = threadIdx.x;

    // level 1: response of e_n -> lo/hi. lvl1[band][m][n] = h[band][n - 2m + 2]
    for (int idx = tid; idx < 2 * 26 * 50; idx += 256) {
        int band = idx / (26 * 50);
        int rem  = idx - band * 26 * 50;
        int m = rem / 50, n = rem - m * 50;
        int k = n - 2 * m + 2;
        float v = 0.f;
        if (k >= 0 && k < 4) v = band ? H1R[k] : H0R[k];
        sL1[idx] = v;
    }
    __syncthreads();

    // level 2: lvl2[j2][m][n] = sum_k h[j2&1][k] * lvl1[j2>>1][2m+k-2][n]
    for (int idx = tid; idx < 4 * 14 * 50; idx += 256) {
        int j   = idx / (14 * 50);
        int rem = idx - j * 14 * 50;
        int m = rem / 50, n = rem - m * 50;
        int b = j >> 1, band = j & 1;
        float acc = 0.f;
        #pragma unroll
        for (int k = 0; k < 4; ++k) {
            int p = 2 * m + k - 2;
            if (p >= 0 && p < 26)
                acc += (band ? H1R[k] : H0R[k]) * sL1[(b * 26 + p) * 50 + n];
        }
        sL2[idx] = acc;
    }
    __syncthreads();

    // level 3: A[(j3*8+s)][n]
    for (int idx = tid; idx < 8 * 8 * 50; idx += 256) {
        int j   = idx / (8 * 50);
        int rem = idx - j * 8 * 50;
        int m = rem / 50, n = rem - m * 50;
        int b = j >> 1, band = j & 1;
        float acc = 0.f;
        #pragma unroll
        for (int k = 0; k < 4; ++k) {
            int p = 2 * m + k - 2;
            if (p >= 0 && p < 14)
                acc += (band ? H1R[k] : H0R[k]) * sL2[(b * 14 + p) * 50 + n];
        }
        sA[idx] = acc;   // idx == (j*8 + m)*50 + n
    }
    __syncthreads();

    // fold: M[k][c][n] = sum_{j,s} W[k,192] at [j*24 + c*8 + s] * A[j*8+s][n]
    for (int idx = tid; idx < 750; idx += 256) {
        int k   = idx / 150;
        int rem = idx - k * 150;
        int c = rem / 50, n = rem - c * 50;
        float acc = 0.f;
        #pragma unroll
        for (int j = 0; j < 8; ++j)
            #pragma unroll
            for (int s = 0; s < 8; ++s)
                acc += W[k * 192 + j * 24 + c * 8 + s] * sA[(j * 8 + s) * 50 + n];
        Mout[idx] = acc;
    }
}

// Kernel 2: out[b,k] = bias[k] + sum_i M[k][i] * x[b,i]   (i = c*50+n, 150 per row)
// 64 rows per block, 256 threads: 4 threads per row, each covers a quarter of i.
#define ROWS 64
#define XSTR 151   // padded LDS row stride (odd -> conflict-free strided reads)

__global__ __launch_bounds__(256) void dwt_gemv(const float* __restrict__ x,
                                                const float* __restrict__ M,
                                                const float* __restrict__ bias,
                                                float* __restrict__ out) {
    __shared__ float sM[5 * 152];
    __shared__ float sX[ROWS * XSTR];
    __shared__ float sO[ROWS * 5];
    const int tid = threadIdx.x;

    for (int idx = tid; idx < 750; idx += 256) {
        int k = idx / 150, i = idx - k * 150;
        sM[k * 152 + i] = M[idx];
    }

    const size_t base = (size_t)blockIdx.x * (ROWS * 150);
    for (int idx = tid; idx < ROWS * 150; idx += 256) {
        int r = idx / 150, c = idx - r * 150;
        sX[r * XSTR + c] = x[base + idx];
    }
    __syncthreads();

    const int r = tid >> 2, q = tid & 3;
    const int i0 = q * 38;
    const int i1 = (i0 + 38 < 150) ? (i0 + 38) : 150;
    float a0 = 0.f, a1 = 0.f, a2 = 0.f, a3 = 0.f, a4 = 0.f;
    const float* xr = &sX[r * XSTR];
    for (int i = i0; i < i1; ++i) {
        float xi = xr[i];
        a0 = fmaf(sM[0 * 152 + i], xi, a0);
        a1 = fmaf(sM[1 * 152 + i], xi, a1);
        a2 = fmaf(sM[2 * 152 + i], xi, a2);
        a3 = fmaf(sM[3 * 152 + i], xi, a3);
        a4 = fmaf(sM[4 * 152 + i], xi, a4);
    }
    // reduce across the 4 lanes of this row (adjacent lanes, same wave)
    a0 += __shfl_xor(a0, 1); a0 += __shfl_xor(a0, 2);
    a1 += __shfl_xor(a1, 1); a1 += __shfl_xor(a1, 2);
    a2 += __shfl_xor(a2, 1); a2 += __shfl_xor(a2, 2);
    a3 += __shfl_xor(a3, 1); a3 += __shfl_xor(a3, 2);
    a4 += __shfl_xor(a4, 1); a4 += __shfl_xor(a4, 2);
    if (q == 0) {
        sO[r * 5 + 0] = a0 + bias[0];
        sO[r * 5 + 1] = a1 + bias[1];
        sO[r * 5 + 2] = a2 + bias[2];
        sO[r * 5 + 3] = a3 + bias[3];
        sO[r * 5 + 4] = a4 + bias[4];
    }
    __syncthreads();
    const size_t obase = (size_t)blockIdx.x * (ROWS * 5);
    for (int idx = tid; idx < ROWS * 5; idx += 256)
        out[obase + idx] = sO[idx];
}

extern "C" void kernel_launch(void* const* d_in, const int* in_sizes, int n_in,
                              void* d_out, int out_size, void* d_ws, size_t ws_size,
                              hipStream_t stream) {
    const float* x    = (const float*)d_in[0];   // (131072, 3, 50)
    const float* W    = (const float*)d_in[1];   // (5, 192)
    const float* bias = (const float*)d_in[2];   // (5,)
    float*       out  = (float*)d_out;           // (131072, 5)
    float*       M    = (float*)d_ws;            // 750 floats

    build_M<<<1, 256, 0, stream>>>(W, M);

    const int B = in_sizes[0] / 150;             // 131072
    const int nblocks = B / ROWS;                // 2048
    dwt_gemv<<<nblocks, 256, 0, stream>>>(x, M, bias, out);
}

// Round 2
// 36.490 us; speedup vs baseline: 1.1472x; 1.1472x over previous
//
#include <hip/hip_runtime.h>

// sym2 filters, pre-reversed (pytorch_wavelets cross-correlation convention)
__device__ __constant__ float H0R[4] = { 0.48296291314453416f,  0.8365163037378079f,
                                         0.22414386804185735f, -0.12940952255126037f};
__device__ __constant__ float H1R[4] = {-0.12940952255126037f, -0.22414386804185735f,
                                         0.8365163037378079f,  -0.48296291314453416f};

// Level geometry (N=50): 50 -> 26 -> 14 -> 8, pad = 4 (ph=2) every level, no odd pad.
// Kernel 1: build folded matrix, stored TRANSPOSED: Mt[i][k], i = c*50+n in [0,150), k in [0,5).
__global__ __launch_bounds__(256) void build_M(const float* __restrict__ W,
                                               float* __restrict__ Mt) {
    __shared__ float sL1[2 * 26 * 50];
    __shared__ float sL2[4 * 14 * 50];
    __shared__ float sA [8 * 8 * 50];
    const int tid = threadIdx.x;

    for (int idx = tid; idx < 2 * 26 * 50; idx += 256) {
        int band = idx / (26 * 50);
        int rem  = idx - band * 26 * 50;
        int m = rem / 50, n = rem - m * 50;
        int k = n - 2 * m + 2;
        float v = 0.f;
        if (k >= 0 && k < 4) v = band ? H1R[k] : H0R[k];
        sL1[idx] = v;
    }
    __syncthreads();

    for (int idx = tid; idx < 4 * 14 * 50; idx += 256) {
        int j   = idx / (14 * 50);
        int rem = idx - j * 14 * 50;
        int m = rem / 50, n = rem - m * 50;
        int b = j >> 1, band = j & 1;
        float acc = 0.f;
        #pragma unroll
        for (int k = 0; k < 4; ++k) {
            int p = 2 * m + k - 2;
            if (p >= 0 && p < 26)
                acc += (band ? H1R[k] : H0R[k]) * sL1[(b * 26 + p) * 50 + n];
        }
        sL2[idx] = acc;
    }
    __syncthreads();

    for (int idx = tid; idx < 8 * 8 * 50; idx += 256) {
        int j   = idx / (8 * 50);
        int rem = idx - j * 8 * 50;
        int m = rem / 50, n = rem - m * 50;
        int b = j >> 1, band = j & 1;
        float acc = 0.f;
        #pragma unroll
        for (int k = 0; k < 4; ++k) {
            int p = 2 * m + k - 2;
            if (p >= 0 && p < 14)
                acc += (band ? H1R[k] : H0R[k]) * sL2[(b * 14 + p) * 50 + n];
        }
        sA[idx] = acc;
    }
    __syncthreads();

    for (int idx = tid; idx < 750; idx += 256) {
        int k   = idx / 150;
        int rem = idx - k * 150;   // i = c*50+n
        int c = rem / 50, n = rem - c * 50;
        float acc = 0.f;
        #pragma unroll
        for (int j = 0; j < 8; ++j)
            #pragma unroll
            for (int s = 0; s < 8; ++s)
                acc += W[k * 192 + j * 24 + c * 8 + s] * sA[(j * 8 + s) * 50 + n];
        Mt[rem * 5 + k] = acc;     // transposed
    }
}

// Kernel 2: one thread per batch row. out[r,k] = bias[k] + sum_i Mt[i][k] * x[r,i].
// Mt index is wave-uniform -> scalar loads (s_load); x staged to LDS in 5 chunks
// of 15 float2 per row (linear writes = conflict-free + coalesced global reads;
// reads stride 15 float2 -> 2-way bank aliasing = free).
#define RPB 256   // rows per block == threads per block

__global__ __launch_bounds__(256) void dwt_gemv(const float* __restrict__ x,
                                                const float* __restrict__ Mt,
                                                const float* __restrict__ bias,
                                                float* __restrict__ out) {
    __shared__ float2 sX2[RPB * 15];   // one 30-float chunk for 256 rows (30 KB)
    __shared__ float  sO[RPB * 5];
    const int tid = threadIdx.x;
    const float2* __restrict__ x2 = (const float2*)x;   // 75 float2 per row
    const size_t r0 = (size_t)blockIdx.x * RPB;

    float ax0 = 0.f, ax1 = 0.f, ax2 = 0.f, ax3 = 0.f, ax4 = 0.f;
    float ay0 = 0.f, ay1 = 0.f, ay2 = 0.f, ay3 = 0.f, ay4 = 0.f;

    for (int ch = 0; ch < 5; ++ch) {
        __syncthreads();               // previous chunk's reads complete
        #pragma unroll
        for (int it = 0; it < 15; ++it) {
            int flat = tid + it * 256;          // 0..3839, linear LDS write
            int r    = flat / 15;
            int jj   = flat - r * 15;
            sX2[flat] = x2[(r0 + r) * 75 + ch * 15 + jj];
        }
        __syncthreads();

        const int ib0 = ch * 30 * 5;
        #pragma unroll
        for (int jj = 0; jj < 15; ++jj) {
            float2 xv = sX2[tid * 15 + jj];
            const int ib = ib0 + jj * 10;       // (ch*30 + 2*jj) * 5
            ax0 = fmaf(Mt[ib + 0], xv.x, ax0);
            ax1 = fmaf(Mt[ib + 1], xv.x, ax1);
            ax2 = fmaf(Mt[ib + 2], xv.x, ax2);
            ax3 = fmaf(Mt[ib + 3], xv.x, ax3);
            ax4 = fmaf(Mt[ib + 4], xv.x, ax4);
            ay0 = fmaf(Mt[ib + 5], xv.y, ay0);
            ay1 = fmaf(Mt[ib + 6], xv.y, ay1);
            ay2 = fmaf(Mt[ib + 7], xv.y, ay2);
            ay3 = fmaf(Mt[ib + 8], xv.y, ay3);
            ay4 = fmaf(Mt[ib + 9], xv.y, ay4);
        }
    }

    sO[tid * 5 + 0] = ax0 + ay0 + bias[0];
    sO[tid * 5 + 1] = ax1 + ay1 + bias[1];
    sO[tid * 5 + 2] = ax2 + ay2 + bias[2];
    sO[tid * 5 + 3] = ax3 + ay3 + bias[3];
    sO[tid * 5 + 4] = ax4 + ay4 + bias[4];
    __syncthreads();

    const size_t ob = (size_t)blockIdx.x * (RPB * 5);
    #pragma unroll
    for (int it = 0; it < 5; ++it)
        out[ob + tid + it * 256] = sO[tid + it * 256];
}

extern "C" void kernel_launch(void* const* d_in, const int* in_sizes, int n_in,
                              void* d_out, int out_size, void* d_ws, size_t ws_size,
                              hipStream_t stream) {
    const float* x    = (const float*)d_in[0];   // (131072, 3, 50)
    const float* W    = (const float*)d_in[1];   // (5, 192)
    const float* bias = (const float*)d_in[2];   // (5,)
    float*       out  = (float*)d_out;           // (131072, 5)
    float*       Mt   = (float*)d_ws;            // 750 floats, [150][5]

    build_M<<<1, 256, 0, stream>>>(W, Mt);

    const int B = in_sizes[0] / 150;             // 131072
    dwt_gemv<<<B / RPB, 256, 0, stream>>>(x, Mt, bias, out);
}

// Round 3
// 31.804 us; speedup vs baseline: 1.3163x; 1.1473x over previous
//
#include <hip/hip_runtime.h>

// ---------------------------------------------------------------------------
// Compile-time wavelet-packet response matrix A[64][50]:
// A[j*8+m][n] = coefficient of x[n] in leaf j, sample m (3-level sym2, zero pad).
// Geometry: 50 -> 26 -> 14 -> 8, pad ph=2 both sides at every level (all even).
// y[m] = sum_k h[k] * in[2m+k-2]   (filters pre-reversed, cross-correlation)
// ---------------------------------------------------------------------------
struct Amat { float a[64][50]; };

constexpr Amat makeA() {
    constexpr float h0[4] = { 0.48296291314453416f,  0.8365163037378079f,
                              0.22414386804185735f, -0.12940952255126037f};
    constexpr float h1[4] = {-0.12940952255126037f, -0.22414386804185735f,
                              0.8365163037378079f,  -0.48296291314453416f};
    float L1[2][26][50] = {};
    for (int band = 0; band < 2; ++band)
        for (int m = 0; m < 26; ++m)
            for (int n = 0; n < 50; ++n) {
                int k = n - 2 * m + 2;
                L1[band][m][n] = (k >= 0 && k < 4) ? (band ? h1[k] : h0[k]) : 0.0f;
            }
    float L2[4][14][50] = {};
    for (int j = 0; j < 4; ++j)
        for (int m = 0; m < 14; ++m)
            for (int n = 0; n < 50; ++n) {
                float acc = 0.0f;
                for (int k = 0; k < 4; ++k) {
                    int p = 2 * m + k - 2;
                    if (p >= 0 && p < 26)
                        acc += (j & 1 ? h1[k] : h0[k]) * L1[j >> 1][p][n];
                }
                L2[j][m][n] = acc;
            }
    Amat A = {};
    for (int j = 0; j < 8; ++j)
        for (int m = 0; m < 8; ++m)
            for (int n = 0; n < 50; ++n) {
                float acc = 0.0f;
                for (int k = 0; k < 4; ++k) {
                    int p = 2 * m + k - 2;
                    if (p >= 0 && p < 14)
                        acc += (j & 1 ? h1[k] : h0[k]) * L2[j >> 1][p][n];
                }
                A.a[j * 8 + m][n] = acc;
            }
    return A;
}

__device__ __constant__ Amat cA = makeA();

// ---------------------------------------------------------------------------
// Kernel 1: fold W (5x192) with A into M, stored PAIR-GROUPED in d_ws:
//   Mg[g*12 + p*5 + k] = M[i][k],  i = 2g+p  (i = c*50+n in [0,150), k in [0,5))
// Pad slots g*12+10, g*12+11 are never read.
// ---------------------------------------------------------------------------
__global__ __launch_bounds__(256) void build_M(const float* __restrict__ W,
                                               float* __restrict__ Mg) {
    const int i = threadIdx.x;
    if (i >= 150) return;
    const int c = i / 50, n = i - c * 50;
    float acc0 = 0.f, acc1 = 0.f, acc2 = 0.f, acc3 = 0.f, acc4 = 0.f;
    for (int f = 0; f < 64; ++f) {          // f = j*8 + s
        const float av = cA.a[f][n];
        const int wj = (f >> 3) * 24 + c * 8 + (f & 7);
        acc0 = fmaf(W[0 * 192 + wj], av, acc0);
        acc1 = fmaf(W[1 * 192 + wj], av, acc1);
        acc2 = fmaf(W[2 * 192 + wj], av, acc2);
        acc3 = fmaf(W[3 * 192 + wj], av, acc3);
        acc4 = fmaf(W[4 * 192 + wj], av, acc4);
    }
    const int g = i >> 1, p = i & 1;
    float* dst = &Mg[g * 12 + p * 5];
    dst[0] = acc0; dst[1] = acc1; dst[2] = acc2; dst[3] = acc3; dst[4] = acc4;
}

// ---------------------------------------------------------------------------
// Kernel 2: one thread per batch row, no sync in the main loop.
// out[r,k] = bias[k] + sum_i M[i][k] * x[r,i]
// M from LDS via wave-uniform broadcast reads (conflict-free);
// x straight global->register, 75 float2 per thread (row-contiguous per lane).
// ---------------------------------------------------------------------------
__global__ __launch_bounds__(256) void dwt_gemv(const float* __restrict__ x,
                                                const float* __restrict__ Mg,
                                                const float* __restrict__ bias,
                                                float* __restrict__ out) {
    __shared__ float sM[75 * 12];
    const int tid = threadIdx.x;
    for (int idx = tid; idx < 900; idx += 256) sM[idx] = Mg[idx];
    __syncthreads();

    const size_t r = (size_t)blockIdx.x * 256 + tid;
    const float2* __restrict__ xr = (const float2*)(x + r * 150);  // 8B aligned

    float a0 = 0.f, a1 = 0.f, a2 = 0.f, a3 = 0.f, a4 = 0.f;
    #pragma unroll 25
    for (int g = 0; g < 75; ++g) {
        const float2 xv = xr[g];
        const float4 m0 = *(const float4*)&sM[g * 12 + 0];   // rows 2g (k0..3)
        const float4 m1 = *(const float4*)&sM[g * 12 + 4];   // 2g k4, 2g+1 k0..2
        const float2 m2 = *(const float2*)&sM[g * 12 + 8];   // 2g+1 k3..4
        a0 = fmaf(m0.x, xv.x, a0);
        a1 = fmaf(m0.y, xv.x, a1);
        a2 = fmaf(m0.z, xv.x, a2);
        a3 = fmaf(m0.w, xv.x, a3);
        a4 = fmaf(m1.x, xv.x, a4);
        a0 = fmaf(m1.y, xv.y, a0);
        a1 = fmaf(m1.z, xv.y, a1);
        a2 = fmaf(m1.w, xv.y, a2);
        a3 = fmaf(m2.x, xv.y, a3);
        a4 = fmaf(m2.y, xv.y, a4);
    }

    float* o = &out[r * 5];
    o[0] = a0 + bias[0];
    o[1] = a1 + bias[1];
    o[2] = a2 + bias[2];
    o[3] = a3 + bias[3];
    o[4] = a4 + bias[4];
}

extern "C" void kernel_launch(void* const* d_in, const int* in_sizes, int n_in,
                              void* d_out, int out_size, void* d_ws, size_t ws_size,
                              hipStream_t stream) {
    const float* x    = (const float*)d_in[0];   // (131072, 3, 50)
    const float* W    = (const float*)d_in[1];   // (5, 192)
    const float* bias = (const float*)d_in[2];   // (5,)
    float*       out  = (float*)d_out;           // (131072, 5)
    float*       Mg   = (float*)d_ws;            // 900 floats, pair-grouped

    build_M<<<1, 256, 0, stream>>>(W, Mg);

    const int B = in_sizes[0] / 150;             // 131072
    dwt_gemv<<<B / 256, 256, 0, stream>>>(x, Mg, bias, out);
}